// Round 1
// baseline (2537.770 us; speedup 1.0000x reference)
//
#include <hip/hip_runtime.h>
#include <math.h>

typedef float f4 __attribute__((ext_vector_type(4)));

#define CDIM 512       // channels = heads*dim_head
#define N_TOK 65536    // 4 * 128 * 128
#define IMG 128

// =====================================================================
// Generic fp32 GEMM: C[M,512] = A[M,512] @ B[512,512]
// Tile 128x128, BK=16, 256 threads, 8x8 per thread (2x2 quadrants of 4x4).
// =====================================================================
__global__ __launch_bounds__(256) void gemm_f32_k512(
    const float* __restrict__ A, const float* __restrict__ B,
    float* __restrict__ C) {
  const int bm = blockIdx.x >> 2;   // row tile (M/128 tiles)
  const int bn = blockIdx.x & 3;    // col tile (512/128 = 4)
  __shared__ float As[16][132];     // [k][row], padded 128->132 (bank spread)
  __shared__ float Bs[16][128];     // [k][col]
  const int tid = threadIdx.x;
  const int tx = tid & 15, ty = tid >> 4;
  const int arow = tid >> 2;            // 0..63 (and +64)
  const int akk  = (tid & 3) << 2;      // k sub-offset for A load
  const int bkk  = tid >> 5;            // 0..7 (and +8)
  const int bcol = (tid & 31) << 2;     // col offset for B load
  const float* Ab = A + (size_t)bm * 128 * CDIM;
  const float* Bb = B + bn * 128;

  f4 acc[2][2][4];
#pragma unroll
  for (int qi = 0; qi < 2; ++qi)
#pragma unroll
    for (int qj = 0; qj < 2; ++qj)
#pragma unroll
      for (int i = 0; i < 4; ++i)
#pragma unroll
        for (int c = 0; c < 4; ++c) acc[qi][qj][i][c] = 0.f;

  for (int kb = 0; kb < 32; ++kb) {
    f4 a0 = *(const f4*)(Ab + (size_t)arow * CDIM + kb * 16 + akk);
    f4 a1 = *(const f4*)(Ab + (size_t)(arow + 64) * CDIM + kb * 16 + akk);
    f4 b0 = *(const f4*)(Bb + (size_t)(kb * 16 + bkk) * CDIM + bcol);
    f4 b1 = *(const f4*)(Bb + (size_t)(kb * 16 + bkk + 8) * CDIM + bcol);
    __syncthreads();   // previous iteration's compute done before overwrite
#pragma unroll
    for (int t = 0; t < 4; ++t) {
      As[akk + t][arow] = a0[t];
      As[akk + t][arow + 64] = a1[t];
    }
    *(f4*)&Bs[bkk][bcol] = b0;
    *(f4*)&Bs[bkk + 8][bcol] = b1;
    __syncthreads();
#pragma unroll
    for (int kk = 0; kk < 16; ++kk) {
      f4 av0 = *(const f4*)&As[kk][ty * 4];
      f4 av1 = *(const f4*)&As[kk][ty * 4 + 64];
      f4 bv0 = *(const f4*)&Bs[kk][tx * 4];
      f4 bv1 = *(const f4*)&Bs[kk][tx * 4 + 64];
#pragma unroll
      for (int i = 0; i < 4; ++i) {
        acc[0][0][i] += av0[i] * bv0;
        acc[0][1][i] += av0[i] * bv1;
        acc[1][0][i] += av1[i] * bv0;
        acc[1][1][i] += av1[i] * bv1;
      }
    }
  }
#pragma unroll
  for (int qi = 0; qi < 2; ++qi)
#pragma unroll
    for (int i = 0; i < 4; ++i) {
      size_t row = (size_t)bm * 128 + qi * 64 + ty * 4 + i;
      float* Cr = C + row * CDIM + bn * 128;
      *(f4*)&Cr[tx * 4] = acc[qi][0][i];
      *(f4*)&Cr[tx * 4 + 64] = acc[qi][1][i];
    }
}

// =====================================================================
// Final GEMM: out[n,512] = (V[n,:] * Mask[n,:]) @ Weff[batch] + bias
// Same tiling as above; batch = row/16384 selects Weff.
// =====================================================================
__global__ __launch_bounds__(256) void gemm_vm_k512(
    const float* __restrict__ V, const float* __restrict__ Msk,
    const float* __restrict__ Weff, const float* __restrict__ bias,
    float* __restrict__ C) {
  const int bm = blockIdx.x >> 2;
  const int bn = blockIdx.x & 3;
  const int batch = bm >> 7;  // 16384/128 = 128 row tiles per batch
  __shared__ float As[16][132];
  __shared__ float Bs[16][128];
  const int tid = threadIdx.x;
  const int tx = tid & 15, ty = tid >> 4;
  const int arow = tid >> 2;
  const int akk  = (tid & 3) << 2;
  const int bkk  = tid >> 5;
  const int bcol = (tid & 31) << 2;
  const float* Vb = V + (size_t)bm * 128 * CDIM;
  const float* Mb = Msk + (size_t)bm * 128 * CDIM;
  const float* Bb = Weff + (size_t)batch * CDIM * CDIM + bn * 128;

  f4 acc[2][2][4];
#pragma unroll
  for (int qi = 0; qi < 2; ++qi)
#pragma unroll
    for (int qj = 0; qj < 2; ++qj)
#pragma unroll
      for (int i = 0; i < 4; ++i)
#pragma unroll
        for (int c = 0; c < 4; ++c) acc[qi][qj][i][c] = 0.f;

  for (int kb = 0; kb < 32; ++kb) {
    f4 a0 = *(const f4*)(Vb + (size_t)arow * CDIM + kb * 16 + akk);
    f4 m0 = *(const f4*)(Mb + (size_t)arow * CDIM + kb * 16 + akk);
    f4 a1 = *(const f4*)(Vb + (size_t)(arow + 64) * CDIM + kb * 16 + akk);
    f4 m1 = *(const f4*)(Mb + (size_t)(arow + 64) * CDIM + kb * 16 + akk);
    f4 b0 = *(const f4*)(Bb + (size_t)(kb * 16 + bkk) * CDIM + bcol);
    f4 b1 = *(const f4*)(Bb + (size_t)(kb * 16 + bkk + 8) * CDIM + bcol);
    a0 *= m0;
    a1 *= m1;
    __syncthreads();
#pragma unroll
    for (int t = 0; t < 4; ++t) {
      As[akk + t][arow] = a0[t];
      As[akk + t][arow + 64] = a1[t];
    }
    *(f4*)&Bs[bkk][bcol] = b0;
    *(f4*)&Bs[bkk + 8][bcol] = b1;
    __syncthreads();
#pragma unroll
    for (int kk = 0; kk < 16; ++kk) {
      f4 av0 = *(const f4*)&As[kk][ty * 4];
      f4 av1 = *(const f4*)&As[kk][ty * 4 + 64];
      f4 bv0 = *(const f4*)&Bs[kk][tx * 4];
      f4 bv1 = *(const f4*)&Bs[kk][tx * 4 + 64];
#pragma unroll
      for (int i = 0; i < 4; ++i) {
        acc[0][0][i] += av0[i] * bv0;
        acc[0][1][i] += av0[i] * bv1;
        acc[1][0][i] += av1[i] * bv0;
        acc[1][1][i] += av1[i] * bv1;
      }
    }
  }
  f4 bb0 = *(const f4*)(bias + bn * 128 + tx * 4);
  f4 bb1 = *(const f4*)(bias + bn * 128 + tx * 4 + 64);
#pragma unroll
  for (int qi = 0; qi < 2; ++qi)
#pragma unroll
    for (int i = 0; i < 4; ++i) {
      size_t row = (size_t)bm * 128 + qi * 64 + ty * 4 + i;
      float* Cr = C + row * CDIM + bn * 128;
      *(f4*)&Cr[tx * 4] = acc[qi][0][i] + bb0;
      *(f4*)&Cr[tx * 4 + 64] = acc[qi][1][i] + bb1;
    }
}

// =====================================================================
// Gram partial: per (b,h,chunk) accumulate G[d][e] += K^T Q over 256 rows,
// plus per-column sum-of-squares of Q and K (for l2norm factors).
// gram laid out [b*8+h][64][64]; qss/kss [b*512 + h*64 + col].
// =====================================================================
__global__ __launch_bounds__(256) void gram_partial(
    const float* __restrict__ Q, const float* __restrict__ Km,
    float* __restrict__ gram, float* __restrict__ qss,
    float* __restrict__ kss) {
  const int chunk = blockIdx.x;  // 0..63  (256 rows each)
  const int bh = blockIdx.y;     // 0..31
  const int b = bh >> 3, h = bh & 7;
  __shared__ float Qs[16][64];
  __shared__ float Ks[16][64];
  const int tid = threadIdx.x;
  const int tx = tid & 15, ty = tid >> 4;
  const int lr = tid >> 4;             // load row 0..15
  const int lc = (tid & 15) << 2;      // load col (f4)
  const size_t base = ((size_t)b * 16384 + (size_t)chunk * 256) * CDIM + h * 64;

  f4 acc[4];
#pragma unroll
  for (int i = 0; i < 4; ++i)
#pragma unroll
    for (int c = 0; c < 4; ++c) acc[i][c] = 0.f;
  float sq = 0.f, sk = 0.f;

  for (int s = 0; s < 16; ++s) {
    f4 qv = *(const f4*)(Q + base + (size_t)(s * 16 + lr) * CDIM + lc);
    f4 kv = *(const f4*)(Km + base + (size_t)(s * 16 + lr) * CDIM + lc);
    __syncthreads();
    *(f4*)&Qs[lr][lc] = qv;
    *(f4*)&Ks[lr][lc] = kv;
    __syncthreads();
#pragma unroll
    for (int r = 0; r < 16; ++r) {
      f4 qq = *(const f4*)&Qs[r][tx * 4];
      f4 kk = *(const f4*)&Ks[r][ty * 4];
#pragma unroll
      for (int i = 0; i < 4; ++i) acc[i] += kk[i] * qq;
    }
    if (tid < 64) {
#pragma unroll
      for (int r = 0; r < 16; ++r) { float v = Qs[r][tid]; sq += v * v; }
    } else if (tid < 128) {
#pragma unroll
      for (int r = 0; r < 16; ++r) { float v = Ks[r][tid - 64]; sk += v * v; }
    }
  }
  float* g = gram + (size_t)bh * 4096;
#pragma unroll
  for (int i = 0; i < 4; ++i)
#pragma unroll
    for (int j = 0; j < 4; ++j)
      atomicAdd(&g[(ty * 4 + i) * 64 + tx * 4 + j], acc[i][j]);
  if (tid < 64) atomicAdd(&qss[b * CDIM + h * 64 + tid], sq);
  else if (tid < 128) atomicAdd(&kss[b * CDIM + h * 64 + (tid - 64)], sk);
}

// =====================================================================
// Normalize + rescale + softmax over e (64). One wave per (b,h,d) row.
// =====================================================================
__global__ __launch_bounds__(256) void attn_softmax(
    float* __restrict__ gram, const float* __restrict__ qss,
    const float* __restrict__ kss, const float* __restrict__ rescale) {
  const int row = blockIdx.x * 4 + (threadIdx.x >> 6);  // 0..2047 = bh*64+d
  const int lane = threadIdx.x & 63;
  const int bh = row >> 6, d = row & 63;
  const int b = bh >> 3, h = bh & 7;
  float kn = fmaxf(sqrtf(kss[b * CDIM + h * 64 + d]), 1e-12f);
  float qn = fmaxf(sqrtf(qss[b * CDIM + h * 64 + lane]), 1e-12f);
  float v = gram[(size_t)row * 64 + lane] / (kn * qn) * rescale[h];
  float m = v;
#pragma unroll
  for (int off = 32; off; off >>= 1) m = fmaxf(m, __shfl_xor(m, off));
  float e = expf(v - m);
  float s = e;
#pragma unroll
  for (int off = 32; off; off >>= 1) s += __shfl_xor(s, off);
  gram[(size_t)row * 64 + lane] = e / s;
}

// =====================================================================
// Weff[b][h*64+e][j] = sum_d attn[b,h,d,e] * Wp[h*64+d][j]
// One block per (b, i=h*64+e); 256 threads cover j (2 each).
// =====================================================================
__global__ __launch_bounds__(256) void build_weff(
    const float* __restrict__ attn, const float* __restrict__ Wp,
    float* __restrict__ weff) {
  const int gid = blockIdx.x;   // 0..2047
  const int b = gid >> 9;
  const int i = gid & 511;
  const int h = i >> 6, e = i & 63;
  __shared__ float a_s[64];
  const int tid = threadIdx.x;
  if (tid < 64) a_s[tid] = attn[((size_t)(b * 8 + h) * 64 + tid) * 64 + e];
  __syncthreads();
  const float* wp = Wp + (size_t)(h * 64) * CDIM;
  float acc0 = 0.f, acc1 = 0.f;
#pragma unroll 8
  for (int d = 0; d < 64; ++d) {
    float a = a_s[d];
    acc0 += a * wp[(size_t)d * CDIM + tid];
    acc1 += a * wp[(size_t)d * CDIM + tid + 256];
  }
  float* wr = weff + ((size_t)b * CDIM + i) * CDIM;
  wr[tid] = acc0;
  wr[tid + 256] = acc1;
}

// =====================================================================
// Depthwise 3x3 convs on NHWC [4,128,128,512], fp32, SAME padding.
// =====================================================================
__device__ inline float gelu_tanh(float x) {
  float x3 = x * x * x;
  return 0.5f * x * (1.f + tanhf(0.7978845608028654f * (x + 0.044715f * x3)));
}

__global__ __launch_bounds__(256) void dwconv_gelu(
    const float* __restrict__ in, const float* __restrict__ w,
    float* __restrict__ out) {
  const int gid = blockIdx.x * 256 + threadIdx.x;  // 8,388,608 total
  const int c4 = gid & 127;
  const int x = (gid >> 7) & 127;
  const int y = (gid >> 14) & 127;
  const int b = gid >> 21;
  const int c = c4 << 2;
  f4 acc;
#pragma unroll
  for (int cc = 0; cc < 4; ++cc) acc[cc] = 0.f;
#pragma unroll
  for (int ky = 0; ky < 3; ++ky) {
    const int yy = y + ky - 1;
    if (yy < 0 || yy > 127) continue;
#pragma unroll
    for (int kx = 0; kx < 3; ++kx) {
      const int xx = x + kx - 1;
      if (xx < 0 || xx > 127) continue;
      f4 v = *(const f4*)(in + (((size_t)b * IMG + yy) * IMG + xx) * CDIM + c);
#pragma unroll
      for (int cc = 0; cc < 4; ++cc)
        acc[cc] += v[cc] * w[(c + cc) * 9 + ky * 3 + kx];
    }
  }
  f4 o;
#pragma unroll
  for (int cc = 0; cc < 4; ++cc) o[cc] = gelu_tanh(acc[cc]);
  *(f4*)(out + (((size_t)b * IMG + y) * IMG + x) * CDIM + c) = o;
}

__global__ __launch_bounds__(256) void dwconv_add(
    const float* __restrict__ in, const float* __restrict__ w,
    float* __restrict__ out) {
  const int gid = blockIdx.x * 256 + threadIdx.x;
  const int c4 = gid & 127;
  const int x = (gid >> 7) & 127;
  const int y = (gid >> 14) & 127;
  const int b = gid >> 21;
  const int c = c4 << 2;
  f4 acc;
#pragma unroll
  for (int cc = 0; cc < 4; ++cc) acc[cc] = 0.f;
#pragma unroll
  for (int ky = 0; ky < 3; ++ky) {
    const int yy = y + ky - 1;
    if (yy < 0 || yy > 127) continue;
#pragma unroll
    for (int kx = 0; kx < 3; ++kx) {
      const int xx = x + kx - 1;
      if (xx < 0 || xx > 127) continue;
      f4 v = *(const f4*)(in + (((size_t)b * IMG + yy) * IMG + xx) * CDIM + c);
#pragma unroll
      for (int cc = 0; cc < 4; ++cc)
        acc[cc] += v[cc] * w[(c + cc) * 9 + ky * 3 + kx];
    }
  }
  const size_t off = (((size_t)b * IMG + y) * IMG + x) * CDIM + c;
  f4 prev = *(const f4*)(out + off);
  *(f4*)(out + off) = prev + acc;
}

// =====================================================================
// Launch
// =====================================================================
extern "C" void kernel_launch(void* const* d_in, const int* in_sizes, int n_in,
                              void* d_out, int out_size, void* d_ws,
                              size_t ws_size, hipStream_t stream) {
  const float* x    = (const float*)d_in[0];
  const float* mask = (const float*)d_in[1];
  const float* Wq   = (const float*)d_in[2];
  const float* Wk   = (const float*)d_in[3];
  const float* Wv   = (const float*)d_in[4];
  const float* resc = (const float*)d_in[5];
  const float* Wp   = (const float*)d_in[6];
  const float* bp   = (const float*)d_in[7];
  const float* w1   = (const float*)d_in[8];
  const float* w2   = (const float*)d_in[9];
  float* out = (float*)d_out;
  float* ws = (float*)d_ws;

  // workspace layout (floats); total ~101.8M floats ~= 389 MiB
  float* q_ws = ws;                       // [65536][512]  (reused as conv t1)
  float* k_ws = q_ws + (size_t)N_TOK * CDIM;
  float* v_ws = k_ws + (size_t)N_TOK * CDIM;
  float* gram = v_ws + (size_t)N_TOK * CDIM;  // [32][64][64]
  float* qss  = gram + 32 * 64 * 64;          // [4][512]
  float* kss  = qss + 4 * CDIM;               // [4][512]
  float* weff = kss + 4 * CDIM;               // [4][512][512]

  // zero the atomic accumulators (gram, qss, kss are contiguous)
  hipMemsetAsync(gram, 0, (32 * 64 * 64 + 2 * 4 * CDIM) * sizeof(float),
                 stream);

  // 1) q/k/v projections
  gemm_f32_k512<<<2048, 256, 0, stream>>>(x, Wq, q_ws);
  gemm_f32_k512<<<2048, 256, 0, stream>>>(x, Wk, k_ws);
  gemm_f32_k512<<<2048, 256, 0, stream>>>(x, Wv, v_ws);

  // 2) Gram matrices + column sumsq (for l2norm), then softmax
  gram_partial<<<dim3(64, 32), 256, 0, stream>>>(q_ws, k_ws, gram, qss, kss);
  attn_softmax<<<512, 256, 0, stream>>>(gram, qss, kss, resc);

  // 3) fold attn into Wp
  build_weff<<<2048, 256, 0, stream>>>(gram, Wp, weff);

  // 4) positional branch: t1 = gelu(dwconv(v)); q_ws is dead, reuse it
  dwconv_gelu<<<32768, 256, 0, stream>>>(v_ws, w1, q_ws);

  // 5) out = (v*mask) @ Weff[b] + bias
  gemm_vm_k512<<<2048, 256, 0, stream>>>(v_ws, mask, weff, bp, out);

  // 6) out += dwconv(t1)
  dwconv_add<<<32768, 256, 0, stream>>>(q_ws, w2, out);
}

// Round 2
// 1591.331 us; speedup vs baseline: 1.5947x; 1.5947x over previous
//
#include <hip/hip_runtime.h>
#include <math.h>

typedef float f4 __attribute__((ext_vector_type(4)));
typedef float f32x4 __attribute__((ext_vector_type(4)));
typedef short s8v __attribute__((ext_vector_type(8)));
typedef unsigned short us4 __attribute__((ext_vector_type(4)));

#define CDIM 512
#define N_TOK 65536
#define IMG 128

// ---------------- bf16 split helpers (round-to-nearest-even-ish) ----------
__device__ inline unsigned short bf16h(float x) {
  unsigned u = __float_as_uint(x);
  u += 0x7FFFu + ((u >> 16) & 1u);
  return (unsigned short)(u >> 16);
}
__device__ inline float bf16f(unsigned short h) {
  return __uint_as_float(((unsigned)h) << 16);
}
__device__ inline void split2(float x, unsigned short& h, unsigned short& l) {
  h = bf16h(x);
  l = bf16h(x - bf16f(h));
}

// =====================================================================
// Pack kernel: WT_{h,l}[which][n][k] = split(W[k][n]) for Wq,Wk,Wv
// =====================================================================
__global__ __launch_bounds__(256) void wt_pack(
    const float* __restrict__ Wq, const float* __restrict__ Wk,
    const float* __restrict__ Wv, unsigned short* __restrict__ WTh,
    unsigned short* __restrict__ WTl) {
  const int bid = blockIdx.x;
  const int which = bid >> 6;
  const int t = bid & 63;
  const int kt = t >> 3, nt = t & 7;
  const float* W = which == 0 ? Wq : (which == 1 ? Wk : Wv);
  __shared__ float ts[64][65];
  const int tid = threadIdx.x;
  const int r = tid >> 4, c4 = (tid & 15) << 2;
#pragma unroll
  for (int i = 0; i < 4; ++i) {
    const int rr = r + i * 16;
    *(f4*)&ts[rr][c4] =
        *(const f4*)(W + (size_t)(kt * 64 + rr) * CDIM + nt * 64 + c4);
  }
  __syncthreads();
  unsigned short* oh = WTh + (size_t)which * CDIM * CDIM;
  unsigned short* ol = WTl + (size_t)which * CDIM * CDIM;
#pragma unroll
  for (int i = 0; i < 4; ++i) {
    const int nn = r + i * 16;
    us4 h, l;
#pragma unroll
    for (int j = 0; j < 4; ++j) {
      unsigned short hh, ll;
      split2(ts[c4 + j][nn], hh, ll);
      h[j] = hh;
      l[j] = ll;
    }
    *(us4*)&oh[(size_t)(nt * 64 + nn) * CDIM + kt * 64 + c4] = h;
    *(us4*)&ol[(size_t)(nt * 64 + nn) * CDIM + kt * 64 + c4] = l;
  }
}

// =====================================================================
// MFMA split-bf16 GEMM, q/k/v fused: C[which][65536,512] = x @ W[which]
// 128x128 tile, BK=32, 4 waves (2x2), per-wave 64x64 = 4x4 frags 16x16x32.
// =====================================================================
__global__ __launch_bounds__(256) void gemm_mfma_proj(
    const float* __restrict__ A, const unsigned short* __restrict__ WTh,
    const unsigned short* __restrict__ WTl, float* __restrict__ Cq,
    float* __restrict__ Ck, float* __restrict__ Cv) {
  const int bid = blockIdx.x;
  const int rt = bid / 12;
  const int rem = bid - rt * 12;
  const int which = rem >> 2;
  const int bn = rem & 3;

  __shared__ unsigned short Ah[128][40];
  __shared__ unsigned short Al[128][40];
  __shared__ unsigned short Bh[128][40];
  __shared__ unsigned short Bl[128][40];

  const int tid = threadIdx.x;
  const int lane = tid & 63, wid = tid >> 6;
  const int wr = wid >> 1, wc = wid & 1;
  const int fr = lane & 15, kh = lane >> 4;

  const float* Ab = A + (size_t)rt * 128 * CDIM;
  const unsigned short* Bhb = WTh + ((size_t)which * CDIM + bn * 128) * CDIM;
  const unsigned short* Blb = WTl + ((size_t)which * CDIM + bn * 128) * CDIM;

  const int ar = tid >> 3, ac = (tid & 7) << 2;
  const int br = tid >> 2, bc = (tid & 3) << 3;

  f32x4 acc[4][4];
#pragma unroll
  for (int mi = 0; mi < 4; ++mi)
#pragma unroll
    for (int ni = 0; ni < 4; ++ni)
#pragma unroll
      for (int r = 0; r < 4; ++r) acc[mi][ni][r] = 0.f;

  for (int kb = 0; kb < 16; ++kb) {
    const int k0 = kb * 32;
    f4 va[4];
    s8v vbh[2], vbl[2];
#pragma unroll
    for (int it = 0; it < 4; ++it)
      va[it] = *(const f4*)(Ab + (size_t)(ar + it * 32) * CDIM + k0 + ac);
#pragma unroll
    for (int it = 0; it < 2; ++it) {
      vbh[it] = *(const s8v*)(Bhb + (size_t)(br + it * 64) * CDIM + k0 + bc);
      vbl[it] = *(const s8v*)(Blb + (size_t)(br + it * 64) * CDIM + k0 + bc);
    }
    __syncthreads();
#pragma unroll
    for (int it = 0; it < 4; ++it) {
      us4 h, l;
#pragma unroll
      for (int j = 0; j < 4; ++j) {
        unsigned short hh, ll;
        split2(va[it][j], hh, ll);
        h[j] = hh;
        l[j] = ll;
      }
      *(us4*)&Ah[ar + it * 32][ac] = h;
      *(us4*)&Al[ar + it * 32][ac] = l;
    }
#pragma unroll
    for (int it = 0; it < 2; ++it) {
      *(s8v*)&Bh[br + it * 64][bc] = vbh[it];
      *(s8v*)&Bl[br + it * 64][bc] = vbl[it];
    }
    __syncthreads();
    s8v fah[4], fal[4], fbh[4], fbl[4];
#pragma unroll
    for (int mi = 0; mi < 4; ++mi) {
      fah[mi] = *(const s8v*)&Ah[wr * 64 + mi * 16 + fr][kh * 8];
      fal[mi] = *(const s8v*)&Al[wr * 64 + mi * 16 + fr][kh * 8];
    }
#pragma unroll
    for (int ni = 0; ni < 4; ++ni) {
      fbh[ni] = *(const s8v*)&Bh[wc * 64 + ni * 16 + fr][kh * 8];
      fbl[ni] = *(const s8v*)&Bl[wc * 64 + ni * 16 + fr][kh * 8];
    }
#pragma unroll
    for (int mi = 0; mi < 4; ++mi)
#pragma unroll
      for (int ni = 0; ni < 4; ++ni) {
        acc[mi][ni] = __builtin_amdgcn_mfma_f32_16x16x32_bf16(
            fah[mi], fbh[ni], acc[mi][ni], 0, 0, 0);
        acc[mi][ni] = __builtin_amdgcn_mfma_f32_16x16x32_bf16(
            fah[mi], fbl[ni], acc[mi][ni], 0, 0, 0);
        acc[mi][ni] = __builtin_amdgcn_mfma_f32_16x16x32_bf16(
            fal[mi], fbh[ni], acc[mi][ni], 0, 0, 0);
      }
  }
  float* C = which == 0 ? Cq : (which == 1 ? Ck : Cv);
#pragma unroll
  for (int mi = 0; mi < 4; ++mi) {
    const int row = rt * 128 + wr * 64 + mi * 16 + kh * 4;
#pragma unroll
    for (int ni = 0; ni < 4; ++ni) {
      const int col = bn * 128 + wc * 64 + ni * 16 + fr;
#pragma unroll
      for (int r = 0; r < 4; ++r)
        C[(size_t)(row + r) * CDIM + col] = acc[mi][ni][r];
    }
  }
}

// =====================================================================
// MFMA split-bf16 GEMM: out[n,512] = (V*Mask) @ WeffT[batch]^T + bias
// WeffT stored [batch][j=512][i=512] bf16 hi/lo (i.e. B^T row-major).
// =====================================================================
__global__ __launch_bounds__(256) void gemm_mfma_vm(
    const float* __restrict__ V, const float* __restrict__ Msk,
    const unsigned short* __restrict__ Eh, const unsigned short* __restrict__ El,
    const float* __restrict__ bias, float* __restrict__ C) {
  const int bid = blockIdx.x;
  const int rt = bid >> 2;
  const int bn = bid & 3;
  const int batch = rt >> 7;

  __shared__ unsigned short Ah[128][40];
  __shared__ unsigned short Al[128][40];
  __shared__ unsigned short Bh[128][40];
  __shared__ unsigned short Bl[128][40];

  const int tid = threadIdx.x;
  const int lane = tid & 63, wid = tid >> 6;
  const int wr = wid >> 1, wc = wid & 1;
  const int fr = lane & 15, kh = lane >> 4;

  const float* Vb = V + (size_t)rt * 128 * CDIM;
  const float* Mb = Msk + (size_t)rt * 128 * CDIM;
  const unsigned short* Bhb = Eh + ((size_t)batch * CDIM + bn * 128) * CDIM;
  const unsigned short* Blb = El + ((size_t)batch * CDIM + bn * 128) * CDIM;

  const int ar = tid >> 3, ac = (tid & 7) << 2;
  const int br = tid >> 2, bc = (tid & 3) << 3;

  f32x4 acc[4][4];
#pragma unroll
  for (int mi = 0; mi < 4; ++mi)
#pragma unroll
    for (int ni = 0; ni < 4; ++ni)
#pragma unroll
      for (int r = 0; r < 4; ++r) acc[mi][ni][r] = 0.f;

  for (int kb = 0; kb < 16; ++kb) {
    const int k0 = kb * 32;
    f4 va[4], vm[4];
    s8v vbh[2], vbl[2];
#pragma unroll
    for (int it = 0; it < 4; ++it) {
      va[it] = *(const f4*)(Vb + (size_t)(ar + it * 32) * CDIM + k0 + ac);
      vm[it] = *(const f4*)(Mb + (size_t)(ar + it * 32) * CDIM + k0 + ac);
    }
#pragma unroll
    for (int it = 0; it < 2; ++it) {
      vbh[it] = *(const s8v*)(Bhb + (size_t)(br + it * 64) * CDIM + k0 + bc);
      vbl[it] = *(const s8v*)(Blb + (size_t)(br + it * 64) * CDIM + k0 + bc);
    }
    __syncthreads();
#pragma unroll
    for (int it = 0; it < 4; ++it) {
      us4 h, l;
#pragma unroll
      for (int j = 0; j < 4; ++j) {
        unsigned short hh, ll;
        split2(va[it][j] * vm[it][j], hh, ll);
        h[j] = hh;
        l[j] = ll;
      }
      *(us4*)&Ah[ar + it * 32][ac] = h;
      *(us4*)&Al[ar + it * 32][ac] = l;
    }
#pragma unroll
    for (int it = 0; it < 2; ++it) {
      *(s8v*)&Bh[br + it * 64][bc] = vbh[it];
      *(s8v*)&Bl[br + it * 64][bc] = vbl[it];
    }
    __syncthreads();
    s8v fah[4], fal[4], fbh[4], fbl[4];
#pragma unroll
    for (int mi = 0; mi < 4; ++mi) {
      fah[mi] = *(const s8v*)&Ah[wr * 64 + mi * 16 + fr][kh * 8];
      fal[mi] = *(const s8v*)&Al[wr * 64 + mi * 16 + fr][kh * 8];
    }
#pragma unroll
    for (int ni = 0; ni < 4; ++ni) {
      fbh[ni] = *(const s8v*)&Bh[wc * 64 + ni * 16 + fr][kh * 8];
      fbl[ni] = *(const s8v*)&Bl[wc * 64 + ni * 16 + fr][kh * 8];
    }
#pragma unroll
    for (int mi = 0; mi < 4; ++mi)
#pragma unroll
      for (int ni = 0; ni < 4; ++ni) {
        acc[mi][ni] = __builtin_amdgcn_mfma_f32_16x16x32_bf16(
            fah[mi], fbh[ni], acc[mi][ni], 0, 0, 0);
        acc[mi][ni] = __builtin_amdgcn_mfma_f32_16x16x32_bf16(
            fah[mi], fbl[ni], acc[mi][ni], 0, 0, 0);
        acc[mi][ni] = __builtin_amdgcn_mfma_f32_16x16x32_bf16(
            fal[mi], fbh[ni], acc[mi][ni], 0, 0, 0);
      }
  }
#pragma unroll
  for (int mi = 0; mi < 4; ++mi) {
    const int row = rt * 128 + wr * 64 + mi * 16 + kh * 4;
#pragma unroll
    for (int ni = 0; ni < 4; ++ni) {
      const int col = bn * 128 + wc * 64 + ni * 16 + fr;
      const float bb = bias[col];
#pragma unroll
      for (int r = 0; r < 4; ++r)
        C[(size_t)(row + r) * CDIM + col] = acc[mi][ni][r] + bb;
    }
  }
}

// =====================================================================
// Gram partial: per (b,h,chunk) accumulate G[d][e] += K^T Q over 256 rows,
// plus per-column sum-of-squares of Q and K (for l2norm factors).
// =====================================================================
__global__ __launch_bounds__(256) void gram_partial(
    const float* __restrict__ Q, const float* __restrict__ Km,
    float* __restrict__ gram, float* __restrict__ qss,
    float* __restrict__ kss) {
  const int chunk = blockIdx.x;  // 0..63  (256 rows each)
  const int bh = blockIdx.y;     // 0..31
  const int b = bh >> 3, h = bh & 7;
  __shared__ float Qs[16][64];
  __shared__ float Ks[16][64];
  const int tid = threadIdx.x;
  const int tx = tid & 15, ty = tid >> 4;
  const int lr = tid >> 4;
  const int lc = (tid & 15) << 2;
  const size_t base = ((size_t)b * 16384 + (size_t)chunk * 256) * CDIM + h * 64;

  f4 acc[4];
#pragma unroll
  for (int i = 0; i < 4; ++i)
#pragma unroll
    for (int c = 0; c < 4; ++c) acc[i][c] = 0.f;
  float sq = 0.f, sk = 0.f;

  for (int s = 0; s < 16; ++s) {
    f4 qv = *(const f4*)(Q + base + (size_t)(s * 16 + lr) * CDIM + lc);
    f4 kv = *(const f4*)(Km + base + (size_t)(s * 16 + lr) * CDIM + lc);
    __syncthreads();
    *(f4*)&Qs[lr][lc] = qv;
    *(f4*)&Ks[lr][lc] = kv;
    __syncthreads();
#pragma unroll
    for (int r = 0; r < 16; ++r) {
      f4 qq = *(const f4*)&Qs[r][tx * 4];
      f4 kk = *(const f4*)&Ks[r][ty * 4];
#pragma unroll
      for (int i = 0; i < 4; ++i) acc[i] += kk[i] * qq;
    }
    if (tid < 64) {
#pragma unroll
      for (int r = 0; r < 16; ++r) { float v = Qs[r][tid]; sq += v * v; }
    } else if (tid < 128) {
#pragma unroll
      for (int r = 0; r < 16; ++r) { float v = Ks[r][tid - 64]; sk += v * v; }
    }
  }
  float* g = gram + (size_t)bh * 4096;
#pragma unroll
  for (int i = 0; i < 4; ++i)
#pragma unroll
    for (int j = 0; j < 4; ++j)
      atomicAdd(&g[(ty * 4 + i) * 64 + tx * 4 + j], acc[i][j]);
  if (tid < 64) atomicAdd(&qss[b * CDIM + h * 64 + tid], sq);
  else if (tid < 128) atomicAdd(&kss[b * CDIM + h * 64 + (tid - 64)], sk);
}

// =====================================================================
// Normalize + rescale + softmax over e (64). One wave per (b,h,d) row.
// =====================================================================
__global__ __launch_bounds__(256) void attn_softmax(
    float* __restrict__ gram, const float* __restrict__ qss,
    const float* __restrict__ kss, const float* __restrict__ rescale) {
  const int row = blockIdx.x * 4 + (threadIdx.x >> 6);
  const int lane = threadIdx.x & 63;
  const int bh = row >> 6, d = row & 63;
  const int b = bh >> 3, h = bh & 7;
  float kn = fmaxf(sqrtf(kss[b * CDIM + h * 64 + d]), 1e-12f);
  float qn = fmaxf(sqrtf(qss[b * CDIM + h * 64 + lane]), 1e-12f);
  float v = gram[(size_t)row * 64 + lane] / (kn * qn) * rescale[h];
  float m = v;
#pragma unroll
  for (int off = 32; off; off >>= 1) m = fmaxf(m, __shfl_xor(m, off));
  float e = expf(v - m);
  float s = e;
#pragma unroll
  for (int off = 32; off; off >>= 1) s += __shfl_xor(s, off);
  gram[(size_t)row * 64 + lane] = e / s;
}

// =====================================================================
// WeffT[b][j][h*64+e] = sum_d attn[b,h,d,e] * Wp[h*64+d][j]  (bf16 hi/lo)
// One block per (b,h).
// =====================================================================
__global__ __launch_bounds__(256) void build_weffT(
    const float* __restrict__ attn, const float* __restrict__ Wp,
    unsigned short* __restrict__ Eh, unsigned short* __restrict__ El) {
  const int b = blockIdx.x >> 3, h = blockIdx.x & 7;
  __shared__ float a_s[64][64];
  const int tid = threadIdx.x;
  const float* ablk = attn + (size_t)(b * 8 + h) * 4096;
#pragma unroll
  for (int i = 0; i < 16; ++i) {
    const int idx = tid + i * 256;
    a_s[idx >> 6][idx & 63] = ablk[idx];
  }
  __syncthreads();
#pragma unroll
  for (int jl = 0; jl < 2; ++jl) {
    const int j = tid + jl * 256;
    f4 acc[16];
#pragma unroll
    for (int e = 0; e < 16; ++e)
#pragma unroll
      for (int c = 0; c < 4; ++c) acc[e][c] = 0.f;
#pragma unroll 4
    for (int d = 0; d < 64; ++d) {
      const float w = Wp[(size_t)(h * 64 + d) * CDIM + j];
#pragma unroll
      for (int e = 0; e < 16; ++e) acc[e] += w * *(const f4*)&a_s[d][e * 4];
    }
    unsigned short* ohp = Eh + ((size_t)b * CDIM + j) * CDIM + h * 64;
    unsigned short* olp = El + ((size_t)b * CDIM + j) * CDIM + h * 64;
#pragma unroll
    for (int e = 0; e < 16; ++e) {
      us4 hh, ll;
#pragma unroll
      for (int c = 0; c < 4; ++c) {
        unsigned short x, y;
        split2(acc[e][c], x, y);
        hh[c] = x;
        ll[c] = y;
      }
      *(us4*)&ohp[e * 4] = hh;
      *(us4*)&olp[e * 4] = ll;
    }
  }
}

// =====================================================================
// Depthwise 3x3 convs on NHWC [4,128,128,512], fp32, SAME padding.
// =====================================================================
__device__ inline float gelu_tanh(float x) {
  float x3 = x * x * x;
  return 0.5f * x * (1.f + tanhf(0.7978845608028654f * (x + 0.044715f * x3)));
}

__global__ __launch_bounds__(256) void dwconv_gelu(
    const float* __restrict__ in, const float* __restrict__ w,
    float* __restrict__ out) {
  const int gid = blockIdx.x * 256 + threadIdx.x;
  const int c4 = gid & 127;
  const int x = (gid >> 7) & 127;
  const int y = (gid >> 14) & 127;
  const int b = gid >> 21;
  const int c = c4 << 2;
  f4 acc;
#pragma unroll
  for (int cc = 0; cc < 4; ++cc) acc[cc] = 0.f;
#pragma unroll
  for (int ky = 0; ky < 3; ++ky) {
    const int yy = y + ky - 1;
    if (yy < 0 || yy > 127) continue;
#pragma unroll
    for (int kx = 0; kx < 3; ++kx) {
      const int xx = x + kx - 1;
      if (xx < 0 || xx > 127) continue;
      f4 v = *(const f4*)(in + (((size_t)b * IMG + yy) * IMG + xx) * CDIM + c);
#pragma unroll
      for (int cc = 0; cc < 4; ++cc)
        acc[cc] += v[cc] * w[(c + cc) * 9 + ky * 3 + kx];
    }
  }
  f4 o;
#pragma unroll
  for (int cc = 0; cc < 4; ++cc) o[cc] = gelu_tanh(acc[cc]);
  *(f4*)(out + (((size_t)b * IMG + y) * IMG + x) * CDIM + c) = o;
}

__global__ __launch_bounds__(256) void dwconv_add(
    const float* __restrict__ in, const float* __restrict__ w,
    float* __restrict__ out) {
  const int gid = blockIdx.x * 256 + threadIdx.x;
  const int c4 = gid & 127;
  const int x = (gid >> 7) & 127;
  const int y = (gid >> 14) & 127;
  const int b = gid >> 21;
  const int c = c4 << 2;
  f4 acc;
#pragma unroll
  for (int cc = 0; cc < 4; ++cc) acc[cc] = 0.f;
#pragma unroll
  for (int ky = 0; ky < 3; ++ky) {
    const int yy = y + ky - 1;
    if (yy < 0 || yy > 127) continue;
#pragma unroll
    for (int kx = 0; kx < 3; ++kx) {
      const int xx = x + kx - 1;
      if (xx < 0 || xx > 127) continue;
      f4 v = *(const f4*)(in + (((size_t)b * IMG + yy) * IMG + xx) * CDIM + c);
#pragma unroll
      for (int cc = 0; cc < 4; ++cc)
        acc[cc] += v[cc] * w[(c + cc) * 9 + ky * 3 + kx];
    }
  }
  const size_t off = (((size_t)b * IMG + y) * IMG + x) * CDIM + c;
  f4 prev = *(const f4*)(out + off);
  *(f4*)(out + off) = prev + acc;
}

// =====================================================================
// Launch
// =====================================================================
extern "C" void kernel_launch(void* const* d_in, const int* in_sizes, int n_in,
                              void* d_out, int out_size, void* d_ws,
                              size_t ws_size, hipStream_t stream) {
  const float* x    = (const float*)d_in[0];
  const float* mask = (const float*)d_in[1];
  const float* Wq   = (const float*)d_in[2];
  const float* Wk   = (const float*)d_in[3];
  const float* Wv   = (const float*)d_in[4];
  const float* resc = (const float*)d_in[5];
  const float* Wp   = (const float*)d_in[6];
  const float* bp   = (const float*)d_in[7];
  const float* w1   = (const float*)d_in[8];
  const float* w2   = (const float*)d_in[9];
  float* out = (float*)d_out;
  float* ws = (float*)d_ws;

  // workspace layout (same footprint as round 1: ~388 MiB)
  float* q_ws = ws;                            // [65536][512] (reused as conv t1)
  float* k_ws = q_ws + (size_t)N_TOK * CDIM;
  float* v_ws = k_ws + (size_t)N_TOK * CDIM;
  float* gram = v_ws + (size_t)N_TOK * CDIM;   // [32][64][64]
  float* qss  = gram + 32 * 64 * 64;           // [4][512]
  float* kss  = qss + 4 * CDIM;                // [4][512]
  // union region (4 MB): packed weights (phase 1) then WeffT (phase 2)
  unsigned short* wTh = (unsigned short*)(kss + 4 * CDIM);  // 3*512*512 us
  unsigned short* wTl = wTh + 3 * CDIM * CDIM;              // 3*512*512 us
  unsigned short* weffTh = (unsigned short*)(kss + 4 * CDIM);  // 4*512*512 us
  unsigned short* weffTl = weffTh + 4 * CDIM * CDIM;           // 4*512*512 us

  hipMemsetAsync(gram, 0, (32 * 64 * 64 + 2 * 4 * CDIM) * sizeof(float),
                 stream);

  // 0) pack + transpose + bf16-split weights
  wt_pack<<<192, 256, 0, stream>>>(Wq, Wk, Wv, wTh, wTl);

  // 1) q/k/v projections (one fused launch, MFMA split-bf16)
  gemm_mfma_proj<<<6144, 256, 0, stream>>>(x, wTh, wTl, q_ws, k_ws, v_ws);

  // 2) Gram matrices + column sumsq, then softmax
  gram_partial<<<dim3(64, 32), 256, 0, stream>>>(q_ws, k_ws, gram, qss, kss);
  attn_softmax<<<512, 256, 0, stream>>>(gram, qss, kss, resc);

  // 3) fold attn into Wp -> WeffT bf16 hi/lo (overlays dead wT region)
  build_weffT<<<32, 256, 0, stream>>>(gram, Wp, weffTh, weffTl);

  // 4) positional branch: t1 = gelu(dwconv(v)); q_ws dead, reuse
  dwconv_gelu<<<32768, 256, 0, stream>>>(v_ws, w1, q_ws);

  // 5) out = (v*mask) @ WeffT[b]^T + bias   (MFMA split-bf16)
  gemm_mfma_vm<<<2048, 256, 0, stream>>>(v_ws, mask, weffTh, weffTl, bp, out);

  // 6) out += dwconv(t1)
  dwconv_add<<<32768, 256, 0, stream>>>(q_ws, w2, out);
}

// Round 3
// 1395.998 us; speedup vs baseline: 1.8179x; 1.1399x over previous
//
#include <hip/hip_runtime.h>
#include <math.h>

typedef float f4 __attribute__((ext_vector_type(4)));
typedef float f32x4 __attribute__((ext_vector_type(4)));
typedef short s8v __attribute__((ext_vector_type(8)));
typedef unsigned short us4 __attribute__((ext_vector_type(4)));

#define CDIM 512
#define N_TOK 65536
#define IMG 128

// ---------------- bf16 helpers ----------------
__device__ __forceinline__ unsigned short bf16h(float x) {
  unsigned u = __float_as_uint(x);
  u += 0x7FFFu + ((u >> 16) & 1u);
  return (unsigned short)(u >> 16);
}
__device__ __forceinline__ float bf16f(unsigned short h) {
  return __uint_as_float(((unsigned)h) << 16);
}
__device__ __forceinline__ void split2(float x, unsigned short& h,
                                       unsigned short& l) {
  h = bf16h(x);
  l = bf16h(x - bf16f(h));
}

// async global->LDS, 16B per lane (wave-uniform LDS base + lane*16)
__device__ __forceinline__ void gl16(const unsigned short* g,
                                     unsigned short* l) {
  __builtin_amdgcn_global_load_lds(
      (const __attribute__((address_space(1))) unsigned int*)g,
      (__attribute__((address_space(3))) unsigned int*)l, 16, 0, 0);
}

// Tiled layout: matrix [R][512] bf16 stored as 8KB tiles:
//   tile (rt, kb) = 512 chunks of 16B; chunk ci=(r*4+kc) holds
//   row rt*128+r, k = kb*32 + kc*8 .. +7.   (linear, conflict-free for
//   16x16x32 frag reads: lane(fr,kh) -> chunk fr*4+kh, a permutation)

// =====================================================================
// split_x: x fp32 [65536][512] -> xh bf16 tiled. One block per tile.
// =====================================================================
__global__ __launch_bounds__(256) void split_x(const float* __restrict__ x,
                                               unsigned short* __restrict__ xt) {
  const int rt = blockIdx.x >> 4, kb = blockIdx.x & 15;
  const int tid = threadIdx.x;
  unsigned short* dst = xt + (size_t)(rt * 16 + kb) * 4096;
#pragma unroll
  for (int i = 0; i < 2; ++i) {
    const int ci = tid + i * 256;
    const int r = ci >> 2, kc = ci & 3;
    const float* src = x + (size_t)(rt * 128 + r) * CDIM + kb * 32 + kc * 8;
    f4 a = *(const f4*)src;
    f4 b = *(const f4*)(src + 4);
    us4 h0, h1;
#pragma unroll
    for (int j = 0; j < 4; ++j) {
      h0[j] = bf16h(a[j]);
      h1[j] = bf16h(b[j]);
    }
    *(us4*)&dst[ci * 8] = h0;
    *(us4*)&dst[ci * 8 + 4] = h1;
  }
}

// =====================================================================
// vm_split: (v*mask) fp32 -> bf16 tiled.
// =====================================================================
__global__ __launch_bounds__(256) void vm_split(const float* __restrict__ v,
                                                const float* __restrict__ msk,
                                                unsigned short* __restrict__ vt) {
  const int rt = blockIdx.x >> 4, kb = blockIdx.x & 15;
  const int tid = threadIdx.x;
  unsigned short* dst = vt + (size_t)(rt * 16 + kb) * 4096;
#pragma unroll
  for (int i = 0; i < 2; ++i) {
    const int ci = tid + i * 256;
    const int r = ci >> 2, kc = ci & 3;
    const size_t off = (size_t)(rt * 128 + r) * CDIM + kb * 32 + kc * 8;
    f4 a = *(const f4*)(v + off);
    f4 b = *(const f4*)(v + off + 4);
    f4 ma = *(const f4*)(msk + off);
    f4 mb = *(const f4*)(msk + off + 4);
    us4 h0, h1;
#pragma unroll
    for (int j = 0; j < 4; ++j) {
      h0[j] = bf16h(a[j] * ma[j]);
      h1[j] = bf16h(b[j] * mb[j]);
    }
    *(us4*)&dst[ci * 8] = h0;
    *(us4*)&dst[ci * 8 + 4] = h1;
  }
}

// =====================================================================
// wt_pack: W[512][512] (k-major) -> B^T tiled bf16 hi/lo.
// grid 192 = 3 which x 4 bt x 16 kb.
// =====================================================================
__global__ __launch_bounds__(256) void wt_pack(
    const float* __restrict__ Wq, const float* __restrict__ Wk,
    const float* __restrict__ Wv, unsigned short* __restrict__ WTh,
    unsigned short* __restrict__ WTl) {
  const int which = blockIdx.x >> 6;
  const int rem = blockIdx.x & 63;
  const int bt = rem >> 4, kb = rem & 15;
  const float* W = which == 0 ? Wq : (which == 1 ? Wk : Wv);
  unsigned short* dh = WTh + ((size_t)which * 64 + bt * 16 + kb) * 4096;
  unsigned short* dl = WTl + ((size_t)which * 64 + bt * 16 + kb) * 4096;
  const int tid = threadIdx.x;
#pragma unroll
  for (int i = 0; i < 2; ++i) {
    const int ci = tid + i * 256;
    const int r = ci >> 2, kc = ci & 3;
    const int n = bt * 128 + r;
    const int kbase = kb * 32 + kc * 8;
    unsigned short hh[8], ll[8];
#pragma unroll
    for (int j = 0; j < 8; ++j) {
      float w = W[(size_t)(kbase + j) * CDIM + n];
      split2(w, hh[j], ll[j]);
    }
#pragma unroll
    for (int j = 0; j < 8; ++j) {
      dh[ci * 8 + j] = hh[j];
      dl[ci * 8 + j] = ll[j];
    }
  }
}

// =====================================================================
// proj GEMM (2-term split): C = A_bf16 @ (Bh+Bl), 128x128 tile, BK=32.
// A staged via global_load_lds from tiled layout; q,k out bf16; v fp32.
// =====================================================================
__global__ __launch_bounds__(256) void gemm_proj(
    const unsigned short* __restrict__ xt, const unsigned short* __restrict__ WTh,
    const unsigned short* __restrict__ WTl, unsigned short* __restrict__ qb,
    unsigned short* __restrict__ kbo, float* __restrict__ v) {
  const int bid = blockIdx.x;
  const int rt = bid / 12;
  const int rem = bid - rt * 12;
  const int which = rem >> 2, bn = rem & 3;

  __shared__ __attribute__((aligned(16))) unsigned short Ah_s[4096];
  __shared__ __attribute__((aligned(16))) unsigned short Bh_s[4096];
  __shared__ __attribute__((aligned(16))) unsigned short Bl_s[4096];

  const int tid = threadIdx.x, lane = tid & 63, wid = tid >> 6;
  const int wr = wid >> 1, wc = wid & 1;
  const int fr = lane & 15, kh = lane >> 4;

  const unsigned short* Ab = xt + (size_t)rt * 16 * 4096;
  const unsigned short* Bhb = WTh + ((size_t)which * 64 + bn * 16) * 4096;
  const unsigned short* Blb = WTl + ((size_t)which * 64 + bn * 16) * 4096;

  f32x4 acc[4][4];
#pragma unroll
  for (int mi = 0; mi < 4; ++mi)
#pragma unroll
    for (int ni = 0; ni < 4; ++ni)
#pragma unroll
      for (int r = 0; r < 4; ++r) acc[mi][ni][r] = 0.f;

  for (int kbi = 0; kbi < 16; ++kbi) {
    if (kbi) __syncthreads();
    // 24 gl16 calls (3 tiles x 8), 6 per wave; dst is wave-uniform.
    {
      const unsigned short* s0 = Ab + kbi * 4096;
      const unsigned short* s1 = Bhb + kbi * 4096;
      const unsigned short* s2 = Blb + kbi * 4096;
#pragma unroll
      for (int c = 0; c < 6; ++c) {
        const int call = wid * 6 + c;
        const int t = call >> 3, sub = call & 7;
        const unsigned short* src = (t == 0 ? s0 : (t == 1 ? s1 : s2));
        unsigned short* dst = (t == 0 ? Ah_s : (t == 1 ? Bh_s : Bl_s));
        gl16(src + sub * 512 + lane * 8, dst + sub * 512);
      }
    }
    __syncthreads();
    s8v fa[4], fbh[4], fbl[4];
    const unsigned short* ap = &Ah_s[(wr * 64 + fr) * 32 + kh * 8];
    const unsigned short* bhp = &Bh_s[(wc * 64 + fr) * 32 + kh * 8];
    const unsigned short* blp = &Bl_s[(wc * 64 + fr) * 32 + kh * 8];
#pragma unroll
    for (int mi = 0; mi < 4; ++mi) fa[mi] = *(const s8v*)(ap + mi * 512);
#pragma unroll
    for (int ni = 0; ni < 4; ++ni) {
      fbh[ni] = *(const s8v*)(bhp + ni * 512);
      fbl[ni] = *(const s8v*)(blp + ni * 512);
    }
#pragma unroll
    for (int mi = 0; mi < 4; ++mi)
#pragma unroll
      for (int ni = 0; ni < 4; ++ni) {
        acc[mi][ni] = __builtin_amdgcn_mfma_f32_16x16x32_bf16(
            fa[mi], fbh[ni], acc[mi][ni], 0, 0, 0);
        acc[mi][ni] = __builtin_amdgcn_mfma_f32_16x16x32_bf16(
            fa[mi], fbl[ni], acc[mi][ni], 0, 0, 0);
      }
  }

  if (which < 2) {
    unsigned short* C = which == 0 ? qb : kbo;
#pragma unroll
    for (int mi = 0; mi < 4; ++mi) {
      const int row = rt * 128 + wr * 64 + mi * 16 + kh * 4;
#pragma unroll
      for (int ni = 0; ni < 4; ++ni) {
        const int col = bn * 128 + wc * 64 + ni * 16 + fr;
#pragma unroll
        for (int r = 0; r < 4; ++r)
          C[(size_t)(row + r) * CDIM + col] = bf16h(acc[mi][ni][r]);
      }
    }
  } else {
#pragma unroll
    for (int mi = 0; mi < 4; ++mi) {
      const int row = rt * 128 + wr * 64 + mi * 16 + kh * 4;
#pragma unroll
      for (int ni = 0; ni < 4; ++ni) {
        const int col = bn * 128 + wc * 64 + ni * 16 + fr;
#pragma unroll
        for (int r = 0; r < 4; ++r)
          v[(size_t)(row + r) * CDIM + col] = acc[mi][ni][r];
      }
    }
  }
}

// =====================================================================
// vm GEMM (2-term split): out = vm_bf16 @ (WeffT_h+WeffT_l)^T + bias.
// =====================================================================
__global__ __launch_bounds__(256) void gemm_vm(
    const unsigned short* __restrict__ vt, const unsigned short* __restrict__ Eh,
    const unsigned short* __restrict__ El, const float* __restrict__ bias,
    float* __restrict__ out) {
  const int bid = blockIdx.x;
  const int rt = bid >> 2, bn = bid & 3;
  const int batch = rt >> 7;

  __shared__ __attribute__((aligned(16))) unsigned short Ah_s[4096];
  __shared__ __attribute__((aligned(16))) unsigned short Bh_s[4096];
  __shared__ __attribute__((aligned(16))) unsigned short Bl_s[4096];

  const int tid = threadIdx.x, lane = tid & 63, wid = tid >> 6;
  const int wr = wid >> 1, wc = wid & 1;
  const int fr = lane & 15, kh = lane >> 4;

  const unsigned short* Ab = vt + (size_t)rt * 16 * 4096;
  const unsigned short* Bhb = Eh + ((size_t)batch * 64 + bn * 16) * 4096;
  const unsigned short* Blb = El + ((size_t)batch * 64 + bn * 16) * 4096;

  f32x4 acc[4][4];
#pragma unroll
  for (int mi = 0; mi < 4; ++mi)
#pragma unroll
    for (int ni = 0; ni < 4; ++ni)
#pragma unroll
      for (int r = 0; r < 4; ++r) acc[mi][ni][r] = 0.f;

  for (int kbi = 0; kbi < 16; ++kbi) {
    if (kbi) __syncthreads();
    {
      const unsigned short* s0 = Ab + kbi * 4096;
      const unsigned short* s1 = Bhb + kbi * 4096;
      const unsigned short* s2 = Blb + kbi * 4096;
#pragma unroll
      for (int c = 0; c < 6; ++c) {
        const int call = wid * 6 + c;
        const int t = call >> 3, sub = call & 7;
        const unsigned short* src = (t == 0 ? s0 : (t == 1 ? s1 : s2));
        unsigned short* dst = (t == 0 ? Ah_s : (t == 1 ? Bh_s : Bl_s));
        gl16(src + sub * 512 + lane * 8, dst + sub * 512);
      }
    }
    __syncthreads();
    s8v fa[4], fbh[4], fbl[4];
    const unsigned short* ap = &Ah_s[(wr * 64 + fr) * 32 + kh * 8];
    const unsigned short* bhp = &Bh_s[(wc * 64 + fr) * 32 + kh * 8];
    const unsigned short* blp = &Bl_s[(wc * 64 + fr) * 32 + kh * 8];
#pragma unroll
    for (int mi = 0; mi < 4; ++mi) fa[mi] = *(const s8v*)(ap + mi * 512);
#pragma unroll
    for (int ni = 0; ni < 4; ++ni) {
      fbh[ni] = *(const s8v*)(bhp + ni * 512);
      fbl[ni] = *(const s8v*)(blp + ni * 512);
    }
#pragma unroll
    for (int mi = 0; mi < 4; ++mi)
#pragma unroll
      for (int ni = 0; ni < 4; ++ni) {
        acc[mi][ni] = __builtin_amdgcn_mfma_f32_16x16x32_bf16(
            fa[mi], fbh[ni], acc[mi][ni], 0, 0, 0);
        acc[mi][ni] = __builtin_amdgcn_mfma_f32_16x16x32_bf16(
            fa[mi], fbl[ni], acc[mi][ni], 0, 0, 0);
      }
  }
#pragma unroll
  for (int mi = 0; mi < 4; ++mi) {
    const int row = rt * 128 + wr * 64 + mi * 16 + kh * 4;
#pragma unroll
    for (int ni = 0; ni < 4; ++ni) {
      const int col = bn * 128 + wc * 64 + ni * 16 + fr;
      const float bb = bias[col];
#pragma unroll
      for (int r = 0; r < 4; ++r)
        out[(size_t)(row + r) * CDIM + col] = acc[mi][ni][r] + bb;
    }
  }
}

// =====================================================================
// Gram partial (bf16 inputs): G[d][e] += K^T Q over 256-row chunks,
// plus per-column sumsq of Q and K.
// =====================================================================
__global__ __launch_bounds__(256) void gram_partial(
    const unsigned short* __restrict__ Q, const unsigned short* __restrict__ Km,
    float* __restrict__ gram, float* __restrict__ qss,
    float* __restrict__ kss) {
  const int chunk = blockIdx.x;  // 0..63
  const int bh = blockIdx.y;     // 0..31
  const int b = bh >> 3, h = bh & 7;
  __shared__ float Qs[16][64];
  __shared__ float Ks[16][64];
  const int tid = threadIdx.x;
  const int tx = tid & 15, ty = tid >> 4;
  const int lr = tid >> 4;
  const int lc = (tid & 15) << 2;
  const size_t base = ((size_t)b * 16384 + (size_t)chunk * 256) * CDIM + h * 64;

  f4 acc[4];
#pragma unroll
  for (int i = 0; i < 4; ++i)
#pragma unroll
    for (int c = 0; c < 4; ++c) acc[i][c] = 0.f;
  float sq = 0.f, sk = 0.f;

  for (int s = 0; s < 16; ++s) {
    us4 qv = *(const us4*)(Q + base + (size_t)(s * 16 + lr) * CDIM + lc);
    us4 kv = *(const us4*)(Km + base + (size_t)(s * 16 + lr) * CDIM + lc);
    __syncthreads();
#pragma unroll
    for (int j = 0; j < 4; ++j) {
      Qs[lr][lc + j] = bf16f(qv[j]);
      Ks[lr][lc + j] = bf16f(kv[j]);
    }
    __syncthreads();
#pragma unroll
    for (int r = 0; r < 16; ++r) {
      f4 qq = *(const f4*)&Qs[r][tx * 4];
      f4 kk = *(const f4*)&Ks[r][ty * 4];
#pragma unroll
      for (int i = 0; i < 4; ++i) acc[i] += kk[i] * qq;
    }
    if (tid < 64) {
#pragma unroll
      for (int r = 0; r < 16; ++r) { float t = Qs[r][tid]; sq += t * t; }
    } else if (tid < 128) {
#pragma unroll
      for (int r = 0; r < 16; ++r) { float t = Ks[r][tid - 64]; sk += t * t; }
    }
  }
  float* g = gram + (size_t)bh * 4096;
#pragma unroll
  for (int i = 0; i < 4; ++i)
#pragma unroll
    for (int j = 0; j < 4; ++j)
      atomicAdd(&g[(ty * 4 + i) * 64 + tx * 4 + j], acc[i][j]);
  if (tid < 64) atomicAdd(&qss[b * CDIM + h * 64 + tid], sq);
  else if (tid < 128) atomicAdd(&kss[b * CDIM + h * 64 + (tid - 64)], sk);
}

// =====================================================================
// Normalize + rescale + softmax over e (64). One wave per (b,h,d) row.
// =====================================================================
__global__ __launch_bounds__(256) void attn_softmax(
    float* __restrict__ gram, const float* __restrict__ qss,
    const float* __restrict__ kss, const float* __restrict__ rescale) {
  const int row = blockIdx.x * 4 + (threadIdx.x >> 6);
  const int lane = threadIdx.x & 63;
  const int bh = row >> 6, d = row & 63;
  const int b = bh >> 3, h = bh & 7;
  float kn = fmaxf(sqrtf(kss[b * CDIM + h * 64 + d]), 1e-12f);
  float qn = fmaxf(sqrtf(qss[b * CDIM + h * 64 + lane]), 1e-12f);
  float v = gram[(size_t)row * 64 + lane] / (kn * qn) * rescale[h];
  float m = v;
#pragma unroll
  for (int off = 32; off; off >>= 1) m = fmaxf(m, __shfl_xor(m, off));
  float e = expf(v - m);
  float s = e;
#pragma unroll
  for (int off = 32; off; off >>= 1) s += __shfl_xor(s, off);
  gram[(size_t)row * 64 + lane] = e / s;
}

// =====================================================================
// build_weffT: WeffT[b][j][i=h*64+e] = sum_d attn[b,h,d,e]*Wp[h*64+d][j]
// bf16 hi/lo in tiled layout. grid 256 = b(4) x h(8) x jt(8).
// =====================================================================
__global__ __launch_bounds__(256) void build_weffT(
    const float* __restrict__ attn, const float* __restrict__ Wp,
    unsigned short* __restrict__ Eh, unsigned short* __restrict__ El) {
  const int b = blockIdx.x >> 6;
  const int h = (blockIdx.x >> 3) & 7;
  const int jt = blockIdx.x & 7;
  __shared__ float a_s[64][64];
  const int tid = threadIdx.x;
  const float* ablk = attn + (size_t)(b * 8 + h) * 4096;
#pragma unroll
  for (int i = 0; i < 16; ++i) {
    const int idx = tid + i * 256;
    a_s[idx >> 6][idx & 63] = ablk[idx];
  }
  __syncthreads();
  const int jl = tid & 63, eq = tid >> 6;
  const int j = jt * 64 + jl;
  float acc[16];
#pragma unroll
  for (int e = 0; e < 16; ++e) acc[e] = 0.f;
#pragma unroll 8
  for (int d = 0; d < 64; ++d) {
    const float w = Wp[(size_t)(h * 64 + d) * CDIM + j];
#pragma unroll
    for (int e = 0; e < 16; ++e) acc[e] += w * a_s[d][eq * 16 + e];
  }
  const int bt = jt >> 1, r = j & 127;
#pragma unroll
  for (int e = 0; e < 16; ++e) {
    const int ich = h * 64 + eq * 16 + e;
    const int kbq = ich >> 5, kc = (ich >> 3) & 3, w8 = ich & 7;
    unsigned short hh, ll;
    split2(acc[e], hh, ll);
    const size_t idx =
        ((size_t)b * 64 + bt * 16 + kbq) * 4096 + (r * 4 + kc) * 8 + w8;
    Eh[idx] = hh;
    El[idx] = ll;
  }
}

// =====================================================================
// Depthwise 3x3 convs on NHWC [4,128,128,512], fp32, SAME padding.
// =====================================================================
__device__ __forceinline__ float gelu_tanh(float x) {
  float x3 = x * x * x;
  return 0.5f * x * (1.f + tanhf(0.7978845608028654f * (x + 0.044715f * x3)));
}

__global__ __launch_bounds__(256) void dwconv_gelu(
    const float* __restrict__ in, const float* __restrict__ w,
    float* __restrict__ out) {
  const int gid = blockIdx.x * 256 + threadIdx.x;
  const int c4 = gid & 127;
  const int x = (gid >> 7) & 127;
  const int y = (gid >> 14) & 127;
  const int b = gid >> 21;
  const int c = c4 << 2;
  f4 acc;
#pragma unroll
  for (int cc = 0; cc < 4; ++cc) acc[cc] = 0.f;
#pragma unroll
  for (int ky = 0; ky < 3; ++ky) {
    const int yy = y + ky - 1;
    if (yy < 0 || yy > 127) continue;
#pragma unroll
    for (int kx = 0; kx < 3; ++kx) {
      const int xx = x + kx - 1;
      if (xx < 0 || xx > 127) continue;
      f4 v = *(const f4*)(in + (((size_t)b * IMG + yy) * IMG + xx) * CDIM + c);
#pragma unroll
      for (int cc = 0; cc < 4; ++cc)
        acc[cc] += v[cc] * w[(c + cc) * 9 + ky * 3 + kx];
    }
  }
  f4 o;
#pragma unroll
  for (int cc = 0; cc < 4; ++cc) o[cc] = gelu_tanh(acc[cc]);
  *(f4*)(out + (((size_t)b * IMG + y) * IMG + x) * CDIM + c) = o;
}

__global__ __launch_bounds__(256) void dwconv_add(
    const float* __restrict__ in, const float* __restrict__ w,
    float* __restrict__ out) {
  const int gid = blockIdx.x * 256 + threadIdx.x;
  const int c4 = gid & 127;
  const int x = (gid >> 7) & 127;
  const int y = (gid >> 14) & 127;
  const int b = gid >> 21;
  const int c = c4 << 2;
  f4 acc;
#pragma unroll
  for (int cc = 0; cc < 4; ++cc) acc[cc] = 0.f;
#pragma unroll
  for (int ky = 0; ky < 3; ++ky) {
    const int yy = y + ky - 1;
    if (yy < 0 || yy > 127) continue;
#pragma unroll
    for (int kx = 0; kx < 3; ++kx) {
      const int xx = x + kx - 1;
      if (xx < 0 || xx > 127) continue;
      f4 v = *(const f4*)(in + (((size_t)b * IMG + yy) * IMG + xx) * CDIM + c);
#pragma unroll
      for (int cc = 0; cc < 4; ++cc)
        acc[cc] += v[cc] * w[(c + cc) * 9 + ky * 3 + kx];
    }
  }
  const size_t off = (((size_t)b * IMG + y) * IMG + x) * CDIM + c;
  f4 prev = *(const f4*)(out + off);
  *(f4*)(out + off) = prev + acc;
}

// =====================================================================
// Launch
// =====================================================================
extern "C" void kernel_launch(void* const* d_in, const int* in_sizes, int n_in,
                              void* d_out, int out_size, void* d_ws,
                              size_t ws_size, hipStream_t stream) {
  const float* x    = (const float*)d_in[0];
  const float* mask = (const float*)d_in[1];
  const float* Wq   = (const float*)d_in[2];
  const float* Wk   = (const float*)d_in[3];
  const float* Wv   = (const float*)d_in[4];
  const float* resc = (const float*)d_in[5];
  const float* Wp   = (const float*)d_in[6];
  const float* bp   = (const float*)d_in[7];
  const float* w1   = (const float*)d_in[8];
  const float* w2   = (const float*)d_in[9];
  float* out = (float*)d_out;
  char* W = (char*)d_ws;

  // workspace layout (~328 MiB)
  unsigned short* xh  = (unsigned short*)(W);                     // 64 MB tiled
  unsigned short* qb  = (unsigned short*)(W + ((size_t)64 << 20));  // 64 MB [n][512]
  unsigned short* kbf = (unsigned short*)(W + ((size_t)128 << 20)); // 64 MB (vmh later)
  float* v_ws = (float*)(W + ((size_t)192 << 20));                // 128 MB fp32
  float* gram = (float*)(W + ((size_t)320 << 20));                // 512 KB
  float* qss  = gram + 32 * 4096;                                 // 8 KB
  float* kss  = qss + 2048;                                       // 8 KB
  unsigned short* wTh = (unsigned short*)(W + ((size_t)321 << 20)); // 1.5 MB
  unsigned short* wTl = wTh + (size_t)3 * 262144;                 // 1.5 MB
  unsigned short* weh = (unsigned short*)(W + ((size_t)324 << 20)); // 2 MB
  unsigned short* wel = weh + (size_t)4 * 262144;                 // 2 MB
  float* t1 = (float*)W;          // 128 MB overlay (xh+qb dead by then)
  unsigned short* vmh = kbf;      // overlay (k dead after gram)

  hipMemsetAsync(gram, 0, (32 * 4096 + 2 * 2048) * sizeof(float), stream);

  // 0) pre-pack
  split_x<<<8192, 256, 0, stream>>>(x, xh);
  wt_pack<<<192, 256, 0, stream>>>(Wq, Wk, Wv, wTh, wTl);

  // 1) q/k/v projections (MFMA 2-term split; q,k bf16 out)
  gemm_proj<<<6144, 256, 0, stream>>>(xh, wTh, wTl, qb, kbf, v_ws);

  // 2) Gram + column sumsq, softmax
  gram_partial<<<dim3(64, 32), 256, 0, stream>>>(qb, kbf, gram, qss, kss);
  attn_softmax<<<512, 256, 0, stream>>>(gram, qss, kss, resc);

  // 3) fold attn into Wp -> tiled bf16 hi/lo
  build_weffT<<<256, 256, 0, stream>>>(gram, Wp, weh, wel);

  // 4) positional branch part 1 (t1 overlays xh+qb)
  dwconv_gelu<<<32768, 256, 0, stream>>>(v_ws, w1, t1);

  // 5) vm split + out GEMM
  vm_split<<<8192, 256, 0, stream>>>(v_ws, mask, vmh);
  gemm_vm<<<2048, 256, 0, stream>>>(vmh, weh, wel, bp, out);

  // 6) out += dwconv(t1)
  dwconv_add<<<32768, 256, 0, stream>>>(t1, w2, out);
}